// Round 2
// baseline (3723.320 us; speedup 1.0000x reference)
//
#include <hip/hip_runtime.h>
#include <hip/hip_bf16.h>

// Persistent bidirectional LSTM for MI355X. B=32, T=512, H=512.
// 128 persistent WGs (2 dirs x 64) + 128 ballast WGs, fp16 weights in VGPRs.
//
// R5 post-mortem: per-producer flag ring gave only +2% (3784->3711 us).
// R3/R4/R5 all land at 7.2-8.8 us/step despite very different contention
// profiles -> the floor is protocol-independent. Cycle accounting says the
// serial chain (h-store ack + flag propagate/detect + h load + 32 MFMA +
// LDS reduce) is ~4,000 cy ~= 1.7 us at 2.4 GHz; measured 17,400 cy/step.
// Leading hypothesis for the ~4x multiplier: SCLK throttling. The kernel
// runs 128 CUs at VALUBusy 2.6% / MfmaUtil 1.5% (waves ~97% stalled on
// s_waitcnt); if fine-grain DPM drops SCLK under near-idle issue, every
// L3 RTT stretches uniformly -- matching the protocol-independent floor.
// R6: DISCRIMINATING EXPERIMENT. Recurrence path byte-identical to R5;
// add 128 ballast WGs (grid 256, all co-resident: 92 VGPR, 8 KB LDS) that
// saturate VALU issue on the otherwise-idle CUs with 4 independent FMA
// chains, exiting via the existing slot-TDIM flags. If DVFS is the
// multiplier, dur drops to ~2-2.6 ms; if unchanged, throttle is falsified
// and the next round removes the x-phase from the step (xg precompute).

#define HDIM 512
#define TDIM 512
#define BDIM 32
#define NWG  64     // workgroups per direction
#define NBAL 128    // ballast workgroups (SCLK keep-alive)
#define NTHR 256
#define CSTRIDE 16  // ints per counter slot (64 B line padding), modes 1/2
#define FLAGN 64    // one flag word per producer WG, mode 0 (256 B per slot)
#define SLOTS (TDIM + 1)

typedef float f32x4 __attribute__((ext_vector_type(4)));
typedef _Float16 half8 __attribute__((ext_vector_type(8)));
typedef unsigned long long u64x2 __attribute__((ext_vector_type(2)));

#define SLICE_INTS (BDIM * HDIM / 2)   // 8192 ints = 32 KB per (step,dir) slice

__device__ __forceinline__ float sigm(float x) { return 1.f / (1.f + __expf(-x)); }
__device__ __forceinline__ float tanh_f(float x) { return 1.f - 2.f / (__expf(2.f * x) + 1.f); }

// ws layout mode 0: [0, 262656): flags, int flg[(d*SLOTS+s)*FLAGN + w].
//                   [262656,...): hbuf ring slices [t][dir][B][H/2], 2xfp16/int.
// ws layout modes 1/2: [0, 65664): counters int cnt[(d*SLOTS+s)*CSTRIDE]; hbuf after.
__global__ void init_ws_kernel(int* __restrict__ sync, int* __restrict__ hbuf_i,
                               int nzero) {
  int i = blockIdx.x * blockDim.x + threadIdx.x;
  int n = blockDim.x * gridDim.x;
  for (int j = i; j < nzero; j += n)
    __hip_atomic_store(sync + j, 0, __ATOMIC_RELAXED, __HIP_MEMORY_SCOPE_AGENT);
  // slice 0 (both dirs) must be zeros (h0 = 0): first 2*SLICE_INTS ints.
  for (int j = i; j < 2 * SLICE_INTS; j += n)
    __hip_atomic_store(hbuf_i + j, 0, __ATOMIC_RELAXED, __HIP_MEMORY_SCOPE_AGENT);
}

template <int MODE>  // 0 = flag ring, 1 = counter ring, 2 = counter dbuf
__global__ __launch_bounds__(NTHR, 1)
void lstm_kernel(const float* __restrict__ x,
                 const float* __restrict__ WihF, const float* __restrict__ WhhF,
                 const float* __restrict__ bihF, const float* __restrict__ bhhF,
                 const float* __restrict__ WihB, const float* __restrict__ WhhB,
                 const float* __restrict__ bihB, const float* __restrict__ bhhB,
                 float* __restrict__ out,
                 int* __restrict__ sync, int* __restrict__ hbuf) {
  constexpr bool RING = (MODE < 2);
  const int blk = blockIdx.x;
  const int tid = threadIdx.x;
  const int lane = tid & 63;

  if (blk >= 2 * NWG) {
    // ---- ballast: keep SCLK up on the otherwise-idle 128 CUs ----
    // 4 independent dependent-FMA chains -> sustained VALU issue on this
    // SIMD. Exit when both dirs' slot-TDIM publishes are complete (those
    // flags/counters are written unconditionally by every producer WG at
    // s = TDIM-1). Poll every ~3.4 us: negligible traffic, tiny exit lag.
    float v0 = (float)(tid + 1), v1 = v0 * 1.5f, v2 = v0 * 2.5f, v3 = v0 * 3.5f;
    const float a = 1.0000001f, b = 1e-7f;
    for (;;) {
#pragma unroll 64
      for (int i = 0; i < 1024; ++i) {
        v0 = __builtin_fmaf(v0, a, b);
        v1 = __builtin_fmaf(v1, a, b);
        v2 = __builtin_fmaf(v2, a, b);
        v3 = __builtin_fmaf(v3, a, b);
      }
      bool done;
      if (MODE == 0) {
        const int* f0 = sync + (size_t)(0 * SLOTS + TDIM) * FLAGN + lane;
        const int* f1 = sync + (size_t)(1 * SLOTS + TDIM) * FLAGN + lane;
        done = (__hip_atomic_load(f0, __ATOMIC_RELAXED, __HIP_MEMORY_SCOPE_AGENT) != 0) &&
               (__hip_atomic_load(f1, __ATOMIC_RELAXED, __HIP_MEMORY_SCOPE_AGENT) != 0);
      } else {
        const int* c0 = sync + (size_t)(0 * SLOTS + TDIM) * CSTRIDE;
        const int* c1 = sync + (size_t)(1 * SLOTS + TDIM) * CSTRIDE;
        done = (__hip_atomic_load(c0, __ATOMIC_RELAXED, __HIP_MEMORY_SCOPE_AGENT) >= NWG) &&
               (__hip_atomic_load(c1, __ATOMIC_RELAXED, __HIP_MEMORY_SCOPE_AGENT) >= NWG);
      }
      if (__all(done)) break;
    }
    asm volatile("" :: "v"(v0), "v"(v1), "v"(v2), "v"(v3));  // keep chains live
    return;
  }

  const int d = blk & 1;    // direction
  const int w = blk >> 1;   // 0..63: owns h-cols [w*8, w*8+8)
  const int wv = tid >> 6;  // wave 0..3
  const int nt = wv >> 1;   // n-tile (16 gate-cols each)
  const int kh = wv & 1;    // k-half (8 kblocks of 32)

  const float* Wih = d ? WihB : WihF;
  const float* Whh = d ? WhhB : WhhF;
  const float* bih = d ? bihB : bihF;
  const float* bhh = d ? bhhB : bhhF;

  // MFMA 16x16x32 lane roles. A: [m=lane&15][k=quad*8+j]; B: [k=quad*8+j][n=lane&15]
  // C/D: col=lane&15, row=(lane>>4)*4+reg  (m89-verified layouts)
  const int nn = lane & 15;
  const int quad = lane >> 4;
  const int n32 = nt * 16 + nn;        // col within WG's 32 gate-cols
  const int gg = n32 >> 3;             // gate 0..3 (i,f,g,o)
  const int jj = n32 & 7;              // h-col within slice
  const int gc = gg * HDIM + w * 8 + jj;  // global gate-col 0..2047

  // ---- stationary weight fragments (fp16 in VGPRs): 8 kblocks x 2 matrices ----
  half8 wihf[8], whhf[8];
#pragma unroll
  for (int kbi = 0; kbi < 8; ++kbi) {
    const int k0 = (kh * 8 + kbi) * 32 + quad * 8;
    const f32x4* pi = (const f32x4*)(Wih + (size_t)gc * HDIM + k0);
    const f32x4* ph = (const f32x4*)(Whh + (size_t)gc * HDIM + k0);
    f32x4 i0 = pi[0], i1 = pi[1], h0 = ph[0], h1 = ph[1];
    half8 a, b;
#pragma unroll
    for (int j = 0; j < 4; ++j) {
      a[j] = (_Float16)i0[j]; a[4 + j] = (_Float16)i1[j];
      b[j] = (_Float16)h0[j]; b[4 + j] = (_Float16)h1[j];
    }
    wihf[kbi] = a; whhf[kbi] = b;
  }
  // Bias seeded by the kh==0 wave ONLY.
  const float bseed = kh ? 0.f : (bih[gc] + bhh[gc]);

  // cell-update role: one (batch, h-col) per thread; c stays in a register
  const int cb = tid >> 3;
  const int cj = tid & 7;
  const int cmt = cb >> 4;
  const int creg = cb & 3;
  const int crow = (cb & 15) >> 2;
  float c = 0.f;

  __shared__ f32x4 part[8][64];  // [ (nt*2+kh)*2+mt ][lane] partial accs

  const int tstep = d ? -1 : 1;
  int tx = d ? (TDIM - 1) : 0;

  for (int s = 0; s < TDIM; ++s, tx += tstep) {
    f32x4 acc0 = {bseed, bseed, bseed, bseed};
    f32x4 acc1 = acc0;

    // ---- x phase: no cross-WG dependence; overlaps other WGs' step s-1 ----
#pragma unroll
    for (int kbi = 0; kbi < 8; ++kbi) {
      const int k0 = (kh * 8 + kbi) * 32 + quad * 8;
      {
        const f32x4* px = (const f32x4*)(x + ((size_t)nn * TDIM + tx) * HDIM + k0);
        f32x4 u0 = px[0], u1 = px[1];
        half8 ax;
#pragma unroll
        for (int j = 0; j < 4; ++j) { ax[j] = (_Float16)u0[j]; ax[4 + j] = (_Float16)u1[j]; }
        acc0 = __builtin_amdgcn_mfma_f32_16x16x32_f16(ax, wihf[kbi], acc0, 0, 0, 0);
      }
      {
        const f32x4* px = (const f32x4*)(x + ((size_t)(16 + nn) * TDIM + tx) * HDIM + k0);
        f32x4 u0 = px[0], u1 = px[1];
        half8 ax;
#pragma unroll
        for (int j = 0; j < 4; ++j) { ax[j] = (_Float16)u0[j]; ax[4 + j] = (_Float16)u1[j]; }
        acc1 = __builtin_amdgcn_mfma_f32_16x16x32_f16(ax, wihf[kbi], acc1, 0, 0, 0);
      }
    }

    // ---- wait for slice s ----
    if (s > 0) {
      if (MODE == 0) {
        // 64 lanes of wave 0 spin on 64 per-producer flags (4 lines total).
        if (wv == 0) {
          const int* pf = sync + (size_t)(d * SLOTS + s) * FLAGN + lane;
          while (__hip_atomic_load(pf, __ATOMIC_RELAXED, __HIP_MEMORY_SCOPE_AGENT) == 0) {}
        }
      } else {
        if (tid == 0) {
          const int* pc = sync + (size_t)(d * SLOTS + s) * CSTRIDE;
          while (__hip_atomic_load(pc, __ATOMIC_RELAXED, __HIP_MEMORY_SCOPE_AGENT) < NWG) {}
        }
      }
      __syncthreads();  // broadcast + compiler barrier (no hoisting of h loads)
    }

    // ---- h phase ----
    if (RING) {
      // cached loads; addresses unique per step -> no staleness possible.
      const _Float16* hb =
          (const _Float16*)(hbuf + ((size_t)s * 2 + d) * SLICE_INTS);
#pragma unroll
      for (int kbi = 0; kbi < 8; ++kbi) {
        const int k0 = (kh * 8 + kbi) * 32 + quad * 8;
        half8 a0 = *(const half8*)(hb + nn * HDIM + k0);
        acc0 = __builtin_amdgcn_mfma_f32_16x16x32_f16(a0, whhf[kbi], acc0, 0, 0, 0);
        half8 a1 = *(const half8*)(hb + (16 + nn) * HDIM + k0);
        acc1 = __builtin_amdgcn_mfma_f32_16x16x32_f16(a1, whhf[kbi], acc1, 0, 0, 0);
      }
    } else {
      // bypass loads (sc0/sc1) from the coherence point; double buffer.
      const unsigned long long* hb = (const unsigned long long*)(
          hbuf + ((size_t)(s & 1) * 2 + d) * SLICE_INTS);
#pragma unroll
      for (int kbi = 0; kbi < 8; ++kbi) {
        const int k0 = (kh * 8 + kbi) * 32 + quad * 8;  // fp16 idx; /4 -> u64 idx
        {
          const unsigned long long* p = hb + (nn * (HDIM / 4) + (k0 >> 2));
          u64x2 q;
          q[0] = __hip_atomic_load(p, __ATOMIC_RELAXED, __HIP_MEMORY_SCOPE_AGENT);
          q[1] = __hip_atomic_load(p + 1, __ATOMIC_RELAXED, __HIP_MEMORY_SCOPE_AGENT);
          half8 a0 = __builtin_bit_cast(half8, q);
          acc0 = __builtin_amdgcn_mfma_f32_16x16x32_f16(a0, whhf[kbi], acc0, 0, 0, 0);
        }
        {
          const unsigned long long* p = hb + ((16 + nn) * (HDIM / 4) + (k0 >> 2));
          u64x2 q;
          q[0] = __hip_atomic_load(p, __ATOMIC_RELAXED, __HIP_MEMORY_SCOPE_AGENT);
          q[1] = __hip_atomic_load(p + 1, __ATOMIC_RELAXED, __HIP_MEMORY_SCOPE_AGENT);
          half8 a1 = __builtin_bit_cast(half8, q);
          acc1 = __builtin_amdgcn_mfma_f32_16x16x32_f16(a1, whhf[kbi], acc1, 0, 0, 0);
        }
      }
    }

    // ---- cross-wave (k-half) reduction via LDS ----
    part[wv * 2 + 0][lane] = acc0;
    part[wv * 2 + 1][lane] = acc1;
    __syncthreads();

    // ---- cell update: thread (cb, cj) gathers its 4 gates ----
    float gv[4];
#pragma unroll
    for (int g4 = 0; g4 < 4; ++g4) {
      const int n32g = g4 * 8 + cj;
      const int ntg = n32g >> 4;
      const int ng = n32g & 15;
      const int lg = (crow << 4) | ng;
      f32x4 p0 = part[(ntg * 2 + 0) * 2 + cmt][lg];
      f32x4 p1 = part[(ntg * 2 + 1) * 2 + cmt][lg];
      gv[g4] = p0[creg] + p1[creg];
    }
    const float ig = sigm(gv[0]);
    const float fg = sigm(gv[1]);
    const float gt = tanh_f(gv[2]);
    const float og = sigm(gv[3]);
    c = fg * c + ig * gt;
    const float h = og * tanh_f(c);

    // ---- publish h: pack 2xfp16 per int, even lane of each pair stores ----
    const float hn = __shfl_xor(h, 1);  // neighbor's h (adjacent cj)
    {
      const size_t tdst = RING ? (size_t)(s + 1) : (size_t)((s + 1) & 1);
      int* hw = hbuf + (tdst * 2 + d) * SLICE_INTS;
      if (!(tid & 1)) {
        const unsigned lo = (unsigned)__builtin_bit_cast(unsigned short, (_Float16)h);
        const unsigned hi = (unsigned)__builtin_bit_cast(unsigned short, (_Float16)hn);
        const int packed = (int)(lo | (hi << 16));
        __hip_atomic_store(hw + cb * (HDIM / 2) + ((w * 8 + cj) >> 1), packed,
                           __ATOMIC_RELAXED, __HIP_MEMORY_SCOPE_AGENT);
      }
    }

    // __syncthreads emits s_waitcnt vmcnt(0) per wave before s_barrier:
    // all write-through h stores are acked at the coherence point before
    // tid0 publishes the next-step flag/counter.
    __syncthreads();
    if (tid == 0) {
      if (MODE == 0) {
        __hip_atomic_store(sync + (size_t)(d * SLOTS + s + 1) * FLAGN + w, 1,
                           __ATOMIC_RELAXED, __HIP_MEMORY_SCOPE_AGENT);
      } else {
        __hip_atomic_fetch_add(sync + (size_t)(d * SLOTS + s + 1) * CSTRIDE, 1,
                               __ATOMIC_RELAXED, __HIP_MEMORY_SCOPE_AGENT);
      }
    }

    // out store AFTER publish: orderless wrt the sync protocol, drained by
    // the next step's barriers / kernel-end release.
    out[((size_t)cb * TDIM + tx) * (2 * HDIM) + d * HDIM + w * 8 + cj] = h;
  }
}

extern "C" void kernel_launch(void* const* d_in, const int* in_sizes, int n_in,
                              void* d_out, int out_size, void* d_ws, size_t ws_size,
                              hipStream_t stream) {
  const float* x    = (const float*)d_in[0];
  const float* WihF = (const float*)d_in[1];
  const float* WhhF = (const float*)d_in[2];
  const float* bihF = (const float*)d_in[3];
  const float* bhhF = (const float*)d_in[4];
  const float* WihB = (const float*)d_in[5];
  const float* WhhB = (const float*)d_in[6];
  const float* bihB = (const float*)d_in[7];
  const float* bhhB = (const float*)d_in[8];
  float* out = (float*)d_out;

  int* sync = (int*)d_ws;
  const size_t flag_bytes = (size_t)2 * SLOTS * FLAGN * 4;    // 262,656 B
  const size_t cnt_bytes  = (size_t)2 * SLOTS * CSTRIDE * 4;  // 65,664 B
  const size_t ring_payload = (size_t)SLOTS * 2 * SLICE_INTS * 4;
  const size_t ringF_bytes = flag_bytes + ring_payload;
  const size_t ringC_bytes = cnt_bytes + ring_payload;

  const int mode = (ws_size >= ringF_bytes) ? 0 : (ws_size >= ringC_bytes ? 1 : 2);
  int* hbuf = (int*)((char*)d_ws + (mode == 0 ? flag_bytes : cnt_bytes));
  const int nzero = (mode == 0) ? 2 * SLOTS * FLAGN : 2 * SLOTS * CSTRIDE;

  hipLaunchKernelGGL(init_ws_kernel, dim3(256), dim3(NTHR), 0, stream,
                     sync, hbuf, nzero);
  const int grid = 2 * NWG + NBAL;
  if (mode == 0) {
    hipLaunchKernelGGL((lstm_kernel<0>), dim3(grid), dim3(NTHR), 0, stream,
                       x, WihF, WhhF, bihF, bhhF, WihB, WhhB, bihB, bhhB,
                       out, sync, hbuf);
  } else if (mode == 1) {
    hipLaunchKernelGGL((lstm_kernel<1>), dim3(grid), dim3(NTHR), 0, stream,
                       x, WihF, WhhF, bihF, bhhF, WihB, WhhB, bihB, bhhB,
                       out, sync, hbuf);
  } else {
    hipLaunchKernelGGL((lstm_kernel<2>), dim3(grid), dim3(NTHR), 0, stream,
                       x, WihF, WhhF, bihF, bhhF, WihB, WhhB, bihB, bhhB,
                       out, sync, hbuf);
  }
}

// Round 3
// 2952.512 us; speedup vs baseline: 1.2611x; 1.2611x over previous
//
#include <hip/hip_runtime.h>
#include <hip/hip_bf16.h>

// Persistent bidirectional LSTM for MI355X. B=32, T=512, H=512.
//
// R6 post-mortem: ballast WGs raised VALUBusy 2.6->17.3% with ZERO effect on
// dur (3723 us) -> DVFS/SCLK throttling falsified. R3-R6 all sit at ~7.3
// us/step regardless of sync protocol or chip activity.
// Counter evidence: WRITE_SIZE 133MB ~= out(64MiB)+ring(33.6MB)+..., FETCH
// 205MB ~= x(32MB)+ring readback+... -> the sc1 exchange round-trips through
// HBM-class latency (~1-2 kcy/hop), and the x-phase (~1.5 kcy + 16MB/step
// L2/L3 fan-out) sits serially inside every step.
// R7: hoist the input GEMM out of the loop.
//   (a) xg_gemm kernel: xg[d][t][b][2048] fp16 = x @ Wih^T + bih + bhh,
//       one-time 68.7 GFLOP MFMA GEMM (128x128 tile, K=512), ~150-300 us.
//   (b) lstm_rec kernel: waves=(nt,mt), FULL K per wave -> no kh LDS
//       reduction, no part[] barriers. Gate-interleaved columns (gc =
//       (nn&3)*512 + w*8 + jj) put all 4 gates of a (b,jj) in adjacent
//       lanes -> cell update via 3 shfl_xor, intra-wave. acc seeded from
//       xg (4 fp16 gather, prefetched a full step ahead).
//       Exchange protocol byte-identical to R5 (flag ring + cached h ring).
//   ws = 256 MiB (observed via harness fill): flags 0.26MB + ring 33.6MB +
//   xg 128MB = 162MB fits. Fallback: R5 kernel (modes 0/1/2).

#define HDIM 512
#define TDIM 512
#define BDIM 32
#define NWG  64     // workgroups per direction (recurrence)
#define NTHR 256
#define CSTRIDE 16  // ints per counter slot (fallback modes 1/2)
#define FLAGN 64    // one flag word per producer WG
#define SLOTS (TDIM + 1)

typedef float f32x4 __attribute__((ext_vector_type(4)));
typedef _Float16 half8 __attribute__((ext_vector_type(8)));
typedef unsigned long long u64x2 __attribute__((ext_vector_type(2)));

#define SLICE_INTS (BDIM * HDIM / 2)   // 8192 ints = 32 KB per (step,dir) slice

__device__ __forceinline__ float sigm(float x) { return 1.f / (1.f + __expf(-x)); }
__device__ __forceinline__ float tanh_f(float x) { return 1.f - 2.f / (__expf(2.f * x) + 1.f); }

// ws layout (new path): [0, 262656): flags  [262656, +33.6MB): h ring
//                       [+, +128MB): xg fp16 [d][t][b][2048]
__global__ void init_ws_kernel(int* __restrict__ sync, int* __restrict__ hbuf_i,
                               int nzero) {
  int i = blockIdx.x * blockDim.x + threadIdx.x;
  int n = blockDim.x * gridDim.x;
  for (int j = i; j < nzero; j += n)
    __hip_atomic_store(sync + j, 0, __ATOMIC_RELAXED, __HIP_MEMORY_SCOPE_AGENT);
  for (int j = i; j < 2 * SLICE_INTS; j += n)   // slice 0 (h0 = 0), both dirs
    __hip_atomic_store(hbuf_i + j, 0, __ATOMIC_RELAXED, __HIP_MEMORY_SCOPE_AGENT);
}

// ---------------------------------------------------------------------------
// xg precompute GEMM: C[m=(b*512+t)][n=gc] = sum_k x[m][k]*Wih[n][k] + bias.
// A = x viewed as [16384][512] (x's natural layout), B = Wih [2048][512].
// 128x128 tile, BK=32, 4 waves each 64x64 (4x4 16x16x32 fragments).
// Output scattered to xg[d][t][b][2048] fp16 (n-contiguous -> coalesced).
// ---------------------------------------------------------------------------
__global__ __launch_bounds__(NTHR, 1)
void xg_gemm(const float* __restrict__ x,
             const float* __restrict__ WihF, const float* __restrict__ bihF,
             const float* __restrict__ bhhF,
             const float* __restrict__ WihB, const float* __restrict__ bihB,
             const float* __restrict__ bhhB,
             _Float16* __restrict__ xg) {
  const int blk = blockIdx.x;
  const int mb = blk & 127;            // 128 m-tiles of 128
  const int ndb = blk >> 7;            // 0..31
  const int d = ndb >> 4;
  const int nb = ndb & 15;             // 16 n-tiles of 128 per dir
  const float* Wih = d ? WihB : WihF;
  const float* bih = d ? bihB : bihF;
  const float* bhh = d ? bhhB : bhhF;
  const int mbase = mb * 128;
  const int nbase = nb * 128;

  __shared__ _Float16 As[128][40];     // pad 8 halves: rows 80B (16B-aligned)
  __shared__ _Float16 Bs[128][40];

  const int tid = threadIdx.x;
  const int lane = tid & 63;
  const int wv = tid >> 6;
  const int wm = wv >> 1, wn = wv & 1;
  const int ln = lane & 15, quad = lane >> 4;

  f32x4 acc[4][4];
#pragma unroll
  for (int i = 0; i < 4; ++i)
#pragma unroll
    for (int j = 0; j < 4; ++j) acc[i][j] = (f32x4){0.f, 0.f, 0.f, 0.f};

  const int srow = tid >> 1, shalf = tid & 1;

  for (int kt = 0; kt < 16; ++kt) {
    const float* pa = x + (size_t)(mbase + srow) * 512 + kt * 32 + shalf * 16;
    const float* pb = Wih + (size_t)(nbase + srow) * 512 + kt * 32 + shalf * 16;
    f32x4 a0 = ((const f32x4*)pa)[0], a1 = ((const f32x4*)pa)[1];
    f32x4 a2 = ((const f32x4*)pa)[2], a3 = ((const f32x4*)pa)[3];
    f32x4 b0 = ((const f32x4*)pb)[0], b1 = ((const f32x4*)pb)[1];
    f32x4 b2 = ((const f32x4*)pb)[2], b3 = ((const f32x4*)pb)[3];
    half8 alo, ahi, blo, bhi;
#pragma unroll
    for (int j = 0; j < 4; ++j) {
      alo[j] = (_Float16)a0[j]; alo[4 + j] = (_Float16)a1[j];
      ahi[j] = (_Float16)a2[j]; ahi[4 + j] = (_Float16)a3[j];
      blo[j] = (_Float16)b0[j]; blo[4 + j] = (_Float16)b1[j];
      bhi[j] = (_Float16)b2[j]; bhi[4 + j] = (_Float16)b3[j];
    }
    __syncthreads();                   // prior iteration's frag reads done
    *(half8*)&As[srow][shalf * 16] = alo;
    *(half8*)&As[srow][shalf * 16 + 8] = ahi;
    *(half8*)&Bs[srow][shalf * 16] = blo;
    *(half8*)&Bs[srow][shalf * 16 + 8] = bhi;
    __syncthreads();

    half8 af[4], bf[4];
#pragma unroll
    for (int i = 0; i < 4; ++i) {
      af[i] = *(const half8*)&As[wm * 64 + i * 16 + ln][quad * 8];
      bf[i] = *(const half8*)&Bs[wn * 64 + i * 16 + ln][quad * 8];
    }
#pragma unroll
    for (int i = 0; i < 4; ++i)
#pragma unroll
      for (int j = 0; j < 4; ++j)
        acc[i][j] = __builtin_amdgcn_mfma_f32_16x16x32_f16(af[i], bf[j], acc[i][j], 0, 0, 0);
  }

  // epilogue: scatter to xg[d][t][b][2048] fp16, bias added.
  _Float16* xgd = xg + (size_t)d * 512 * 32 * 2048;
#pragma unroll
  for (int j = 0; j < 4; ++j) {
    const int n = nbase + wn * 64 + j * 16 + ln;
    const float bs = bih[n] + bhh[n];
#pragma unroll
    for (int i = 0; i < 4; ++i) {
#pragma unroll
      for (int r = 0; r < 4; ++r) {
        const int m = mbase + wm * 64 + i * 16 + quad * 4 + r;
        const int t = m & 511;
        const int b = m >> 9;
        xgd[(((size_t)t * 32 + b) * 2048) + n] = (_Float16)(acc[i][j][r] + bs);
      }
    }
  }
}

// ---------------------------------------------------------------------------
// Recurrence kernel (new): 128 WGs (2 dirs x 64), 4 waves = (nt, mt),
// full-K per wave, gate-interleaved columns, intra-wave cell update.
// Exchange protocol identical to R5 (flag ring + cached h ring).
// ---------------------------------------------------------------------------
__global__ __launch_bounds__(NTHR, 1)
void lstm_rec(const float* __restrict__ WhhF, const float* __restrict__ WhhB,
              float* __restrict__ out, int* __restrict__ sync,
              int* __restrict__ hbuf, const _Float16* __restrict__ xg) {
  const int blk = blockIdx.x;
  const int d = blk & 1;
  const int w = blk >> 1;            // owns h-cols [w*8, w*8+8)
  const int tid = threadIdx.x;
  const int lane = tid & 63;
  const int wv = tid >> 6;
  const int nt = wv & 1;             // jj-half: jj in [nt*4, nt*4+4)
  const int mt = wv >> 1;            // batch half: b in [mt*16, mt*16+16)
  const float* Whh = d ? WhhB : WhhF;

  const int nn = lane & 15;
  const int quad = lane >> 4;
  const int gg = nn & 3;             // gate 0..3 (i,f,g,o) -- interleaved
  const int jj = nt * 4 + (nn >> 2); // h-col within WG's 8
  const int gc = gg * HDIM + w * 8 + jj;
  const int b0 = mt * 16 + quad * 4; // this thread's 4 batch rows (acc regs)

  // stationary Whh fragments: 16 kblocks, full K=512 per wave. 64 VGPRs.
  half8 whhf[16];
#pragma unroll
  for (int kbi = 0; kbi < 16; ++kbi) {
    const int k0 = kbi * 32 + quad * 8;
    const f32x4* ph = (const f32x4*)(Whh + (size_t)gc * HDIM + k0);
    f32x4 h0 = ph[0], h1 = ph[1];
    half8 b;
#pragma unroll
    for (int j = 0; j < 4; ++j) { b[j] = (_Float16)h0[j]; b[4 + j] = (_Float16)h1[j]; }
    whhf[kbi] = b;
  }

  const _Float16* xgd = xg + (size_t)d * 512 * 32 * 2048;
  const int tstep = d ? -1 : 1;
  int tx = d ? (TDIM - 1) : 0;

  // preload xg for step 0 (4 scalar fp16, b-stride 2048)
  _Float16 xh0, xh1, xh2, xh3;
  {
    const _Float16* xp = xgd + ((size_t)tx * 32 + b0) * 2048 + gc;
    xh0 = xp[0]; xh1 = xp[2048]; xh2 = xp[4096]; xh3 = xp[6144];
  }

  float c0 = 0.f, c1 = 0.f, c2 = 0.f, c3 = 0.f;

  for (int s = 0; s < TDIM; ++s, tx += tstep) {
    f32x4 acc = {(float)xh0, (float)xh1, (float)xh2, (float)xh3};

    // ---- wait for slice s (identical to R5) ----
    if (s > 0) {
      if (wv == 0) {
        const int* pf = sync + (size_t)(d * SLOTS + s) * FLAGN + lane;
        while (__hip_atomic_load(pf, __ATOMIC_RELAXED, __HIP_MEMORY_SCOPE_AGENT) == 0) {}
      }
      __syncthreads();  // broadcast + compiler barrier
    }

    // ---- h-phase: 16 MFMAs, cached ring loads (fresh addresses) ----
    const _Float16* hb = (const _Float16*)(hbuf + ((size_t)s * 2 + d) * SLICE_INTS);
#pragma unroll
    for (int kbi = 0; kbi < 16; ++kbi) {
      const int k0 = kbi * 32 + quad * 8;
      half8 a = *(const half8*)(hb + (mt * 16 + nn) * HDIM + k0);
      acc = __builtin_amdgcn_mfma_f32_16x16x32_f16(a, whhf[kbi], acc, 0, 0, 0);
    }

    // ---- intra-wave cell update. acc[r] = gate gg for (b0+r, jj).
    // Gather the 4 gates from adjacent lanes; results valid on gg==0 lanes
    // (others compute garbage, never stored; their c is dead state). ----
    float h0f, h1f, h2f, h3f;
    {
      float g0, g1, g2, g3, t1, t2;
#define CELL(R, CR, HF)                                                     \
      g0 = acc[R];                                                          \
      t1 = __shfl_xor(acc[R], 1);                                           \
      t2 = __shfl_xor(acc[R], 2);                                           \
      g3 = __shfl_xor(t1, 2);                                               \
      g1 = t1; g2 = t2;                                                     \
      {                                                                     \
        const float iv = sigm(g0), fv = sigm(g1);                           \
        const float gv = tanh_f(g2), ov = sigm(g3);                         \
        CR = fv * CR + iv * gv;                                             \
        HF = ov * tanh_f(CR);                                               \
      }
      CELL(0, c0, h0f) CELL(1, c1, h1f) CELL(2, c2, h2f) CELL(3, c3, h3f)
#undef CELL
    }

    // ---- publish h: pack (jj, jj+1) pairs; storers nn in {0,8} ----
    const float hn0 = __shfl_xor(h0f, 4);
    const float hn1 = __shfl_xor(h1f, 4);
    const float hn2 = __shfl_xor(h2f, 4);
    const float hn3 = __shfl_xor(h3f, 4);
    {
      int* hw = hbuf + ((size_t)(s + 1) * 2 + d) * SLICE_INTS;
      if ((nn & 7) == 0) {
        const int colint = w * 4 + nt * 2 + (nn >> 3);
#define PUB(R, HF, HN)                                                       \
        {                                                                    \
          const unsigned lo = (unsigned)__builtin_bit_cast(unsigned short, (_Float16)(HF)); \
          const unsigned hi = (unsigned)__builtin_bit_cast(unsigned short, (_Float16)(HN)); \
          __hip_atomic_store(hw + (b0 + R) * (HDIM / 2) + colint,            \
                             (int)(lo | (hi << 16)), __ATOMIC_RELAXED,       \
                             __HIP_MEMORY_SCOPE_AGENT);                      \
        }
        PUB(0, h0f, hn0) PUB(1, h1f, hn1) PUB(2, h2f, hn2) PUB(3, h3f, hn3)
#undef PUB
      }
    }

    // drain (vmcnt(0) per wave) so all h stores are at the coherence point
    // before tid0 publishes the flag.
    __syncthreads();
    if (tid == 0)
      __hip_atomic_store(sync + (size_t)(d * SLOTS + s + 1) * FLAGN + w, 1,
                         __ATOMIC_RELAXED, __HIP_MEMORY_SCOPE_AGENT);

    // ---- out store (orderless) + xg prefetch for next step ----
    if (gg == 0) {
      out[((size_t)(b0 + 0) * TDIM + tx) * (2 * HDIM) + d * HDIM + w * 8 + jj] = h0f;
      out[((size_t)(b0 + 1) * TDIM + tx) * (2 * HDIM) + d * HDIM + w * 8 + jj] = h1f;
      out[((size_t)(b0 + 2) * TDIM + tx) * (2 * HDIM) + d * HDIM + w * 8 + jj] = h2f;
      out[((size_t)(b0 + 3) * TDIM + tx) * (2 * HDIM) + d * HDIM + w * 8 + jj] = h3f;
    }
    if (s + 1 < TDIM) {
      const _Float16* xp = xgd + ((size_t)(tx + tstep) * 32 + b0) * 2048 + gc;
      xh0 = xp[0]; xh1 = xp[2048]; xh2 = xp[4096]; xh3 = xp[6144];
    }
  }
}

// ---------------------------------------------------------------------------
// Fallback: R5 kernel verbatim (flag ring / counter ring / dbuf).
// ---------------------------------------------------------------------------
template <int MODE>  // 0 = flag ring, 1 = counter ring, 2 = counter dbuf
__global__ __launch_bounds__(NTHR, 1)
void lstm_kernel(const float* __restrict__ x,
                 const float* __restrict__ WihF, const float* __restrict__ WhhF,
                 const float* __restrict__ bihF, const float* __restrict__ bhhF,
                 const float* __restrict__ WihB, const float* __restrict__ WhhB,
                 const float* __restrict__ bihB, const float* __restrict__ bhhB,
                 float* __restrict__ out,
                 int* __restrict__ sync, int* __restrict__ hbuf) {
  constexpr bool RING = (MODE < 2);
  const int blk = blockIdx.x;
  const int d = blk & 1;
  const int w = blk >> 1;
  const int tid = threadIdx.x;
  const int lane = tid & 63;
  const int wv = tid >> 6;
  const int nt = wv >> 1;
  const int kh = wv & 1;

  const float* Wih = d ? WihB : WihF;
  const float* Whh = d ? WhhB : WhhF;
  const float* bih = d ? bihB : bihF;
  const float* bhh = d ? bhhB : bhhF;

  const int nn = lane & 15;
  const int quad = lane >> 4;
  const int n32 = nt * 16 + nn;
  const int gg = n32 >> 3;
  const int jj = n32 & 7;
  const int gc = gg * HDIM + w * 8 + jj;

  half8 wihf[8], whhf[8];
#pragma unroll
  for (int kbi = 0; kbi < 8; ++kbi) {
    const int k0 = (kh * 8 + kbi) * 32 + quad * 8;
    const f32x4* pi = (const f32x4*)(Wih + (size_t)gc * HDIM + k0);
    const f32x4* ph = (const f32x4*)(Whh + (size_t)gc * HDIM + k0);
    f32x4 i0 = pi[0], i1 = pi[1], h0 = ph[0], h1 = ph[1];
    half8 a, b;
#pragma unroll
    for (int j = 0; j < 4; ++j) {
      a[j] = (_Float16)i0[j]; a[4 + j] = (_Float16)i1[j];
      b[j] = (_Float16)h0[j]; b[4 + j] = (_Float16)h1[j];
    }
    wihf[kbi] = a; whhf[kbi] = b;
  }
  const float bseed = kh ? 0.f : (bih[gc] + bhh[gc]);

  const int cb = tid >> 3;
  const int cj = tid & 7;
  const int cmt = cb >> 4;
  const int creg = cb & 3;
  const int crow = (cb & 15) >> 2;
  float c = 0.f;

  __shared__ f32x4 part[8][64];

  const int tstep = d ? -1 : 1;
  int tx = d ? (TDIM - 1) : 0;

  for (int s = 0; s < TDIM; ++s, tx += tstep) {
    f32x4 acc0 = {bseed, bseed, bseed, bseed};
    f32x4 acc1 = acc0;

#pragma unroll
    for (int kbi = 0; kbi < 8; ++kbi) {
      const int k0 = (kh * 8 + kbi) * 32 + quad * 8;
      {
        const f32x4* px = (const f32x4*)(x + ((size_t)nn * TDIM + tx) * HDIM + k0);
        f32x4 u0 = px[0], u1 = px[1];
        half8 ax;
#pragma unroll
        for (int j = 0; j < 4; ++j) { ax[j] = (_Float16)u0[j]; ax[4 + j] = (_Float16)u1[j]; }
        acc0 = __builtin_amdgcn_mfma_f32_16x16x32_f16(ax, wihf[kbi], acc0, 0, 0, 0);
      }
      {
        const f32x4* px = (const f32x4*)(x + ((size_t)(16 + nn) * TDIM + tx) * HDIM + k0);
        f32x4 u0 = px[0], u1 = px[1];
        half8 ax;
#pragma unroll
        for (int j = 0; j < 4; ++j) { ax[j] = (_Float16)u0[j]; ax[4 + j] = (_Float16)u1[j]; }
        acc1 = __builtin_amdgcn_mfma_f32_16x16x32_f16(ax, wihf[kbi], acc1, 0, 0, 0);
      }
    }

    if (s > 0) {
      if (MODE == 0) {
        if (wv == 0) {
          const int* pf = sync + (size_t)(d * SLOTS + s) * FLAGN + lane;
          while (__hip_atomic_load(pf, __ATOMIC_RELAXED, __HIP_MEMORY_SCOPE_AGENT) == 0) {}
        }
      } else {
        if (tid == 0) {
          const int* pc = sync + (size_t)(d * SLOTS + s) * CSTRIDE;
          while (__hip_atomic_load(pc, __ATOMIC_RELAXED, __HIP_MEMORY_SCOPE_AGENT) < NWG) {}
        }
      }
      __syncthreads();
    }

    if (RING) {
      const _Float16* hb =
          (const _Float16*)(hbuf + ((size_t)s * 2 + d) * SLICE_INTS);
#pragma unroll
      for (int kbi = 0; kbi < 8; ++kbi) {
        const int k0 = (kh * 8 + kbi) * 32 + quad * 8;
        half8 a0 = *(const half8*)(hb + nn * HDIM + k0);
        acc0 = __builtin_amdgcn_mfma_f32_16x16x32_f16(a0, whhf[kbi], acc0, 0, 0, 0);
        half8 a1 = *(const half8*)(hb + (16 + nn) * HDIM + k0);
        acc1 = __builtin_amdgcn_mfma_f32_16x16x32_f16(a1, whhf[kbi], acc1, 0, 0, 0);
      }
    } else {
      const unsigned long long* hb = (const unsigned long long*)(
          hbuf + ((size_t)(s & 1) * 2 + d) * SLICE_INTS);
#pragma unroll
      for (int kbi = 0; kbi < 8; ++kbi) {
        const int k0 = (kh * 8 + kbi) * 32 + quad * 8;
        {
          const unsigned long long* p = hb + (nn * (HDIM / 4) + (k0 >> 2));
          u64x2 q;
          q[0] = __hip_atomic_load(p, __ATOMIC_RELAXED, __HIP_MEMORY_SCOPE_AGENT);
          q[1] = __hip_atomic_load(p + 1, __ATOMIC_RELAXED, __HIP_MEMORY_SCOPE_AGENT);
          half8 a0 = __builtin_bit_cast(half8, q);
          acc0 = __builtin_amdgcn_mfma_f32_16x16x32_f16(a0, whhf[kbi], acc0, 0, 0, 0);
        }
        {
          const unsigned long long* p = hb + ((16 + nn) * (HDIM / 4) + (k0 >> 2));
          u64x2 q;
          q[0] = __hip_atomic_load(p, __ATOMIC_RELAXED, __HIP_MEMORY_SCOPE_AGENT);
          q[1] = __hip_atomic_load(p + 1, __ATOMIC_RELAXED, __HIP_MEMORY_SCOPE_AGENT);
          half8 a1 = __builtin_bit_cast(half8, q);
          acc1 = __builtin_amdgcn_mfma_f32_16x16x32_f16(a1, whhf[kbi], acc1, 0, 0, 0);
        }
      }
    }

    part[wv * 2 + 0][lane] = acc0;
    part[wv * 2 + 1][lane] = acc1;
    __syncthreads();

    float gv[4];
#pragma unroll
    for (int g4 = 0; g4 < 4; ++g4) {
      const int n32g = g4 * 8 + cj;
      const int ntg = n32g >> 4;
      const int ng = n32g & 15;
      const int lg = (crow << 4) | ng;
      f32x4 p0 = part[(ntg * 2 + 0) * 2 + cmt][lg];
      f32x4 p1 = part[(ntg * 2 + 1) * 2 + cmt][lg];
      gv[g4] = p0[creg] + p1[creg];
    }
    const float ig = sigm(gv[0]);
    const float fg = sigm(gv[1]);
    const float gt = tanh_f(gv[2]);
    const float og = sigm(gv[3]);
    c = fg * c + ig * gt;
    const float h = og * tanh_f(c);

    const float hn = __shfl_xor(h, 1);
    {
      const size_t tdst = RING ? (size_t)(s + 1) : (size_t)((s + 1) & 1);
      int* hw = hbuf + (tdst * 2 + d) * SLICE_INTS;
      if (!(tid & 1)) {
        const unsigned lo = (unsigned)__builtin_bit_cast(unsigned short, (_Float16)h);
        const unsigned hi = (unsigned)__builtin_bit_cast(unsigned short, (_Float16)hn);
        const int packed = (int)(lo | (hi << 16));
        __hip_atomic_store(hw + cb * (HDIM / 2) + ((w * 8 + cj) >> 1), packed,
                           __ATOMIC_RELAXED, __HIP_MEMORY_SCOPE_AGENT);
      }
    }

    __syncthreads();
    if (tid == 0) {
      if (MODE == 0) {
        __hip_atomic_store(sync + (size_t)(d * SLOTS + s + 1) * FLAGN + w, 1,
                           __ATOMIC_RELAXED, __HIP_MEMORY_SCOPE_AGENT);
      } else {
        __hip_atomic_fetch_add(sync + (size_t)(d * SLOTS + s + 1) * CSTRIDE, 1,
                               __ATOMIC_RELAXED, __HIP_MEMORY_SCOPE_AGENT);
      }
    }

    out[((size_t)cb * TDIM + tx) * (2 * HDIM) + d * HDIM + w * 8 + cj] = h;
  }
}

extern "C" void kernel_launch(void* const* d_in, const int* in_sizes, int n_in,
                              void* d_out, int out_size, void* d_ws, size_t ws_size,
                              hipStream_t stream) {
  const float* x    = (const float*)d_in[0];
  const float* WihF = (const float*)d_in[1];
  const float* WhhF = (const float*)d_in[2];
  const float* bihF = (const float*)d_in[3];
  const float* bhhF = (const float*)d_in[4];
  const float* WihB = (const float*)d_in[5];
  const float* WhhB = (const float*)d_in[6];
  const float* bihB = (const float*)d_in[7];
  const float* bhhB = (const float*)d_in[8];
  float* out = (float*)d_out;

  int* sync = (int*)d_ws;
  const size_t flag_bytes = (size_t)2 * SLOTS * FLAGN * 4;    // 262,656 B
  const size_t cnt_bytes  = (size_t)2 * SLOTS * CSTRIDE * 4;  // 65,664 B
  const size_t ring_bytes = (size_t)SLOTS * 2 * SLICE_INTS * 4;   // 33.6 MB
  const size_t xg_bytes   = (size_t)2 * 512 * 32 * 2048 * 2;      // 128 MiB
  const size_t new_req = flag_bytes + ring_bytes + xg_bytes;      // ~160.3 MiB

  if (ws_size >= new_req) {
    int* hbuf = (int*)((char*)d_ws + flag_bytes);
    _Float16* xg = (_Float16*)((char*)d_ws + flag_bytes + ring_bytes);
    hipLaunchKernelGGL(init_ws_kernel, dim3(256), dim3(NTHR), 0, stream,
                       sync, hbuf, (int)(2 * SLOTS * FLAGN));
    hipLaunchKernelGGL(xg_gemm, dim3(4096), dim3(NTHR), 0, stream,
                       x, WihF, bihF, bhhF, WihB, bihB, bhhB, xg);
    hipLaunchKernelGGL(lstm_rec, dim3(2 * NWG), dim3(NTHR), 0, stream,
                       WhhF, WhhB, out, sync, hbuf, xg);
    return;
  }

  // fallback tiers (R5)
  const size_t ringF_bytes = flag_bytes + ring_bytes;
  const size_t ringC_bytes = cnt_bytes + ring_bytes;
  const int mode = (ws_size >= ringF_bytes) ? 0 : (ws_size >= ringC_bytes ? 1 : 2);
  int* hbuf = (int*)((char*)d_ws + (mode == 0 ? flag_bytes : cnt_bytes));
  const int nzero = (mode == 0) ? 2 * SLOTS * FLAGN : 2 * SLOTS * CSTRIDE;

  hipLaunchKernelGGL(init_ws_kernel, dim3(256), dim3(NTHR), 0, stream,
                     sync, hbuf, nzero);
  if (mode == 0) {
    hipLaunchKernelGGL((lstm_kernel<0>), dim3(2 * NWG), dim3(NTHR), 0, stream,
                       x, WihF, WhhF, bihF, bhhF, WihB, WhhB, bihB, bhhB,
                       out, sync, hbuf);
  } else if (mode == 1) {
    hipLaunchKernelGGL((lstm_kernel<1>), dim3(2 * NWG), dim3(NTHR), 0, stream,
                       x, WihF, WhhF, bihF, bhhF, WihB, WhhB, bihB, bhhB,
                       out, sync, hbuf);
  } else {
    hipLaunchKernelGGL((lstm_kernel<2>), dim3(2 * NWG), dim3(NTHR), 0, stream,
                       x, WihF, WhhF, bihF, bhhF, WihB, WhhB, bihB, bhhB,
                       out, sync, hbuf);
  }
}